// Round 6
// baseline (567.952 us; speedup 1.0000x reference)
//
#include <hip/hip_runtime.h>
#include <hip/hip_bf16.h>

// GCN encoder: 2x GCNConv, symmetric norm, relu + L2 rownorm between.
// CSR-by-dst build, pull aggregation (no float atomics), bf16 intermediates.
// R5: coarse_scatter still had 12.5x write amp (80MB for 6.4MB) -- cross-XCD
// dirty-line fragmentation (8 per-XCD L2s each writing partial lines).
// Fix: slice each bucket's pair region by blockIdx&7 (XCD heuristic) so each
// XCD writes its own contiguous sub-region; full lines form in one L2.

#define IN_CH 128
#define HID 128
#define OUT_CH 64

typedef unsigned int uint_t;
typedef unsigned short ushort_t;

__device__ __forceinline__ ushort_t f32_to_bf16_rn(float f) {
    uint_t u = __float_as_uint(f);
    u = (u + 0x7fffu + ((u >> 16) & 1u)) >> 16;
    return (ushort_t)u;
}
__device__ __forceinline__ float bf16lo_to_f32(uint_t u) { return __uint_as_float(u << 16); }
__device__ __forceinline__ float bf16hi_to_f32(uint_t u) { return __uint_as_float(u & 0xffff0000u); }

// ---------------- degree histogram + per-(bucket,slice) histogram ----------------
__global__ __launch_bounds__(256) void count_kernel(const int* __restrict__ dst,
                                                    int E, int* __restrict__ cnt,
                                                    int* __restrict__ scnt) {
    int e = blockIdx.x * 256 + threadIdx.x;
    int slice = blockIdx.x & 7;
    if (e < E) {
        int d = dst[e];
        atomicAdd(&cnt[d], 1);
        atomicAdd(&scnt[(d >> 6) * 8 + slice], 1);
    }
}

// ---------------- 3-kernel exclusive scan over cnt[] -> row_start[] ----------------
__global__ __launch_bounds__(256) void scan1_kernel(const int* __restrict__ cnt, int n,
                                                    int* __restrict__ row_start,
                                                    int* __restrict__ bsum) {
    __shared__ int sdata[256];
    int tid = threadIdx.x;
    int i = blockIdx.x * 256 + tid;
    int v = (i < n) ? cnt[i] : 0;
    sdata[tid] = v;
    __syncthreads();
    for (int off = 1; off < 256; off <<= 1) {
        int t = (tid >= off) ? sdata[tid - off] : 0;
        __syncthreads();
        sdata[tid] += t;
        __syncthreads();
    }
    if (i < n) row_start[i] = sdata[tid] - v;
    if (tid == 255) bsum[blockIdx.x] = sdata[255];
}

__global__ __launch_bounds__(512) void scan2_kernel(int* __restrict__ bsum, int nb,
                                                    int* __restrict__ boff) {
    __shared__ int sdata[512];
    int tid = threadIdx.x;
    int v = (tid < nb) ? bsum[tid] : 0;
    sdata[tid] = v;
    __syncthreads();
    for (int off = 1; off < 512; off <<= 1) {
        int t = (tid >= off) ? sdata[tid - off] : 0;
        __syncthreads();
        sdata[tid] += t;
        __syncthreads();
    }
    boff[tid] = sdata[tid] - v;
}

__global__ __launch_bounds__(256) void scan3_kernel(int* __restrict__ row_start,
                                                    const int* __restrict__ boff,
                                                    const int* __restrict__ cnt,
                                                    float* __restrict__ dinv,
                                                    int n, int E) {
    int i = blockIdx.x * 256 + threadIdx.x;
    if (i < n) {
        int rs = row_start[i] + boff[i >> 8];
        row_start[i] = rs;
        dinv[i] = rsqrtf((float)(cnt[i] + 1));  // +1 self loop
    }
    if (i == 0) row_start[n] = E;
}

// ---------------- per-bucket slice cursors: scur[b*8+s] = absolute start -----------
__global__ __launch_bounds__(256) void slice_scan_kernel(const int* __restrict__ row_start,
                                                         const int* __restrict__ scnt,
                                                         int* __restrict__ scur, int NB) {
    int b = blockIdx.x * 256 + threadIdx.x;
    if (b < NB) {
        int base = row_start[b << 6];
        #pragma unroll
        for (int s = 0; s < 8; s++) {
            scur[b * 8 + s] = base;
            base += scnt[b * 8 + s];
        }
    }
}

// ---------------- coarse scatter: edges -> slice-local packed pairs ----------------
// bucket = dst >> 6; slice = blockIdx & 7 (XCD heuristic). Each slice's stores
// go to its private contiguous region -> no cross-XCD line fragmentation.
// pack: src (26 bits) | (dst & 63) << 26.
__global__ __launch_bounds__(256) void coarse_scatter_kernel(const int* __restrict__ src,
                                                             const int* __restrict__ dst,
                                                             int E,
                                                             int* __restrict__ scur,
                                                             uint_t* __restrict__ pairs) {
    int e = blockIdx.x * 256 + threadIdx.x;
    int slice = blockIdx.x & 7;
    if (e < E) {
        int s = src[e];
        int d = dst[e];
        int p = atomicAdd(&scur[(d >> 6) * 8 + slice], 1);
        pairs[p] = (uint_t)s | ((uint_t)(d & 63) << 26);
    }
}

// ---------------- fine fill: one block per bucket, LDS cursors ----------------
__global__ __launch_bounds__(256) void fine_fill_kernel(const uint_t* __restrict__ pairs,
                                                        const int* __restrict__ row_start,
                                                        int* __restrict__ csr_src,
                                                        int n) {
    __shared__ int cur[64];
    int b = blockIdx.x;
    int node0 = b << 6;
    int tid = threadIdx.x;
    if (tid < 64 && node0 + tid < n) cur[tid] = row_start[node0 + tid];
    __syncthreads();
    int start = row_start[node0];
    int nodeEnd = node0 + 64; if (nodeEnd > n) nodeEnd = n;
    int end = row_start[nodeEnd];
    for (int j = start + tid; j < end; j += 256) {
        uint_t u = pairs[j];
        int s = (int)(u & 0x3FFFFFFu);
        int dl = (int)(u >> 26);
        int pos = atomicAdd(&cur[dl], 1);
        csr_src[pos] = s;
    }
}

// ---------------- GEMM: Y[n x NCOL] = X[n x 128] * W[128 x NCOL] ----------------
template <int NCOL, bool BF16_IN>
__global__ __launch_bounds__(256, 3) void gemm_kernel(const void* __restrict__ Xv,
                                                      const float* __restrict__ W,
                                                      ushort_t* __restrict__ Y, int nrows) {
    constexpr int K = 128;
    constexpr int KT = 32;
    constexpr int CPL = NCOL / 64;       // cols per lane (2 or 1)
    __shared__ __align__(16) float Xs[64 * K];      // 32 KB
    __shared__ __align__(16) float Ws[KT * NCOL];   // 16 KB / 8 KB

    int tid = threadIdx.x;
    int wave = tid >> 6;
    int lane = tid & 63;
    int rowBase = blockIdx.x * 64;
    int r0 = wave * 16;

    if (BF16_IN) {
        const uint_t* X = (const uint_t*)Xv;
        for (int j = tid; j < 64 * (K / 2); j += 256) {
            int r = j >> 6;
            int c = j & 63;
            int gr = rowBase + r;
            uint_t u = (gr < nrows) ? X[(size_t)gr * (K / 2) + c] : 0u;
            Xs[r * K + 2 * c]     = bf16lo_to_f32(u);
            Xs[r * K + 2 * c + 1] = bf16hi_to_f32(u);
        }
    } else {
        const float4* X4 = (const float4*)Xv;
        float4* Xs4 = (float4*)Xs;
        for (int j = tid; j < 64 * (K / 4); j += 256) {
            int r = j >> 5;
            int gr = rowBase + r;
            float4 v = make_float4(0.f, 0.f, 0.f, 0.f);
            if (gr < nrows) v = X4[(size_t)gr * (K / 4) + (j & 31)];
            Xs4[j] = v;
        }
    }

    float acc[16][CPL];
    #pragma unroll
    for (int r = 0; r < 16; r++)
        #pragma unroll
        for (int c = 0; c < CPL; c++) acc[r][c] = 0.f;

    #pragma unroll 1
    for (int kt = 0; kt < K; kt += KT) {
        __syncthreads();
        {
            float4* Ws4 = (float4*)Ws;
            const float4* W4 = (const float4*)W;
            for (int j = tid; j < KT * (NCOL / 4); j += 256)
                Ws4[j] = W4[(size_t)kt * (NCOL / 4) + j];
        }
        __syncthreads();
        #pragma unroll 2
        for (int k4 = 0; k4 < KT; k4 += 4) {
            float wv[4][CPL];
            #pragma unroll
            for (int kk = 0; kk < 4; kk++)
                #pragma unroll
                for (int c = 0; c < CPL; c++)
                    wv[kk][c] = Ws[(k4 + kk) * NCOL + lane * CPL + c];
            #pragma unroll
            for (int r = 0; r < 16; r++) {
                float4 xv = *(const float4*)&Xs[(r0 + r) * K + kt + k4];  // broadcast
                #pragma unroll
                for (int c = 0; c < CPL; c++) {
                    acc[r][c] = fmaf(xv.x, wv[0][c], acc[r][c]);
                    acc[r][c] = fmaf(xv.y, wv[1][c], acc[r][c]);
                    acc[r][c] = fmaf(xv.z, wv[2][c], acc[r][c]);
                    acc[r][c] = fmaf(xv.w, wv[3][c], acc[r][c]);
                }
            }
        }
    }

    #pragma unroll
    for (int r = 0; r < 16; r++) {
        int gr = rowBase + r0 + r;
        if (gr < nrows) {
            if (CPL == 2) {
                uint_t u = (uint_t)f32_to_bf16_rn(acc[r][0]) |
                           ((uint_t)f32_to_bf16_rn(acc[r][CPL - 1]) << 16);
                ((uint_t*)(Y + (size_t)gr * NCOL))[lane] = u;
            } else {
                Y[(size_t)gr * NCOL + lane] = f32_to_bf16_rn(acc[r][0]);
            }
        }
    }
}

// ---------------- aggregation layer 1: pull + bias + relu + L2 rownorm ----------------
__global__ __launch_bounds__(256) void agg1_kernel(const ushort_t* __restrict__ xw,
                                                   const int* __restrict__ csr_src,
                                                   const int* __restrict__ row_start,
                                                   const float* __restrict__ dinv,
                                                   const float* __restrict__ b1,
                                                   ushort_t* __restrict__ h, int n) {
    int wid = (blockIdx.x * 256 + threadIdx.x) >> 6;
    int lane = threadIdx.x & 63;
    if (wid >= n) return;
    int i = wid;
    float di = dinv[i];
    float sc = di * di;
    uint_t su = ((const uint_t*)(xw + (size_t)i * HID))[lane];
    float ax = bf16lo_to_f32(su) * sc, ay = bf16hi_to_f32(su) * sc;
    int e0 = row_start[i], e1 = row_start[i + 1];
    int e = e0;
    for (; e + 8 <= e1; e += 8) {
        int s[8];
        #pragma unroll
        for (int j = 0; j < 8; j++) s[j] = csr_src[e + j];
        float dv[8];
        #pragma unroll
        for (int j = 0; j < 8; j++) dv[j] = dinv[s[j]];
        uint_t v[8];
        #pragma unroll
        for (int j = 0; j < 8; j++)
            v[j] = ((const uint_t*)(xw + (size_t)s[j] * HID))[lane];
        #pragma unroll
        for (int j = 0; j < 8; j++) {
            float c = dv[j] * di;
            ax = fmaf(bf16lo_to_f32(v[j]), c, ax);
            ay = fmaf(bf16hi_to_f32(v[j]), c, ay);
        }
    }
    for (; e < e1; e++) {
        int s = csr_src[e];
        float c = dinv[s] * di;
        uint_t v = ((const uint_t*)(xw + (size_t)s * HID))[lane];
        ax = fmaf(bf16lo_to_f32(v), c, ax);
        ay = fmaf(bf16hi_to_f32(v), c, ay);
    }
    ax += b1[lane * 2];
    ay += b1[lane * 2 + 1];
    ax = fmaxf(ax, 0.f);
    ay = fmaxf(ay, 0.f);
    float ss = ax * ax + ay * ay;
    #pragma unroll
    for (int m = 32; m >= 1; m >>= 1) ss += __shfl_xor(ss, m, 64);
    float scale = 1.0f / fmaxf(sqrtf(ss), 1e-12f);
    uint_t u = (uint_t)f32_to_bf16_rn(ax * scale) |
               ((uint_t)f32_to_bf16_rn(ay * scale) << 16);
    ((uint_t*)(h + (size_t)i * HID))[lane] = u;
}

// ---------------- aggregation layer 2: pull + bias -> d_out (f32) ----------------
__global__ __launch_bounds__(256) void agg2_kernel(const ushort_t* __restrict__ hw,
                                                   const int* __restrict__ csr_src,
                                                   const int* __restrict__ row_start,
                                                   const float* __restrict__ dinv,
                                                   const float* __restrict__ b2,
                                                   float* __restrict__ out, int n) {
    int wid = (blockIdx.x * 256 + threadIdx.x) >> 6;
    int lane = threadIdx.x & 63;
    int i = wid * 2 + (lane >> 5);
    int l = lane & 31;
    if (i >= n) return;
    float di = dinv[i];
    float sc = di * di;
    uint_t su = ((const uint_t*)(hw + (size_t)i * OUT_CH))[l];
    float ax = bf16lo_to_f32(su) * sc, ay = bf16hi_to_f32(su) * sc;
    int e0 = row_start[i], e1 = row_start[i + 1];
    int e = e0;
    for (; e + 8 <= e1; e += 8) {
        int s[8];
        #pragma unroll
        for (int j = 0; j < 8; j++) s[j] = csr_src[e + j];
        float dv[8];
        #pragma unroll
        for (int j = 0; j < 8; j++) dv[j] = dinv[s[j]];
        uint_t v[8];
        #pragma unroll
        for (int j = 0; j < 8; j++)
            v[j] = ((const uint_t*)(hw + (size_t)s[j] * OUT_CH))[l];
        #pragma unroll
        for (int j = 0; j < 8; j++) {
            float c = dv[j] * di;
            ax = fmaf(bf16lo_to_f32(v[j]), c, ax);
            ay = fmaf(bf16hi_to_f32(v[j]), c, ay);
        }
    }
    for (; e < e1; e++) {
        int s = csr_src[e];
        float c = dinv[s] * di;
        uint_t v = ((const uint_t*)(hw + (size_t)s * OUT_CH))[l];
        ax = fmaf(bf16lo_to_f32(v), c, ax);
        ay = fmaf(bf16hi_to_f32(v), c, ay);
    }
    ax += b2[l * 2];
    ay += b2[l * 2 + 1];
    ((float2*)(out + (size_t)i * OUT_CH))[l] = make_float2(ax, ay);
}

extern "C" void kernel_launch(void* const* d_in, const int* in_sizes, int n_in,
                              void* d_out, int out_size, void* d_ws, size_t ws_size,
                              hipStream_t stream) {
    const float* x  = (const float*)d_in[0];
    const int*   ei = (const int*)d_in[1];
    const float* W1 = (const float*)d_in[2];
    const float* b1 = (const float*)d_in[3];
    const float* W2 = (const float*)d_in[4];
    const float* b2 = (const float*)d_in[5];
    float* out = (float*)d_out;

    const int N = in_sizes[0] / IN_CH;     // 100000
    const int E = in_sizes[1] / 2;         // 1600000
    const int* src = ei;
    const int* dst = ei + E;
    const int NB = (N + 63) / 64;          // coarse buckets (1563)

    // ---- workspace carve ----
    char* base = (char*)d_ws;
    size_t off = 0;
    auto alloc = [&](size_t bytes) -> void* {
        void* p = base + off;
        off = (off + bytes + 255) & ~(size_t)255;
        return p;
    };
    int*      cnt       = (int*)alloc((size_t)N * 4);
    int*      row_start = (int*)alloc((size_t)(N + 1) * 4);
    int*      bsum      = (int*)alloc(512 * 4);
    int*      boff      = (int*)alloc(512 * 4);
    float*    dinv      = (float*)alloc((size_t)N * 4);
    int*      csr_src   = (int*)alloc((size_t)E * 4);
    uint_t*   pairs     = (uint_t*)alloc((size_t)E * 4);
    int*      scnt      = (int*)alloc((size_t)NB * 8 * 4);
    int*      scur      = (int*)alloc((size_t)NB * 8 * 4);
    ushort_t* xw        = (ushort_t*)alloc((size_t)N * HID * 2);
    ushort_t* h         = (ushort_t*)alloc((size_t)N * HID * 2);
    ushort_t* hw        = (ushort_t*)alloc((size_t)N * OUT_CH * 2);
    (void)ws_size;

    const int nb = (N + 255) / 256;

    hipMemsetAsync(cnt, 0, (size_t)N * 4, stream);
    hipMemsetAsync(scnt, 0, (size_t)NB * 8 * 4, stream);

    count_kernel<<<(E + 255) / 256, 256, 0, stream>>>(dst, E, cnt, scnt);

    scan1_kernel<<<nb, 256, 0, stream>>>(cnt, N, row_start, bsum);
    scan2_kernel<<<1, 512, 0, stream>>>(bsum, nb, boff);
    scan3_kernel<<<nb, 256, 0, stream>>>(row_start, boff, cnt, dinv, N, E);

    slice_scan_kernel<<<(NB + 255) / 256, 256, 0, stream>>>(row_start, scnt, scur, NB);

    coarse_scatter_kernel<<<(E + 255) / 256, 256, 0, stream>>>(src, dst, E, scur, pairs);
    fine_fill_kernel<<<NB, 256, 0, stream>>>(pairs, row_start, csr_src, N);

    gemm_kernel<128, false><<<(N + 63) / 64, 256, 0, stream>>>(x, W1, xw, N);

    agg1_kernel<<<(N * 64 + 255) / 256, 256, 0, stream>>>(xw, csr_src, row_start,
                                                          dinv, b1, h, N);

    gemm_kernel<64, true><<<(N + 63) / 64, 256, 0, stream>>>(h, W2, hw, N);

    int waves2 = (N + 1) / 2;
    agg2_kernel<<<(waves2 * 64 + 255) / 256, 256, 0, stream>>>(hw, csr_src, row_start,
                                                               dinv, b2, out, N);
}

// Round 7
// 382.813 us; speedup vs baseline: 1.4836x; 1.4836x over previous
//
#include <hip/hip_runtime.h>
#include <hip/hip_bf16.h>

// GCN encoder: 2x GCNConv, symmetric norm, relu + L2 rownorm between.
// Pull aggregation over CSR-by-dst, bf16 intermediates (f32 accumulate).
// R6 lesson: device-scope global atomics are memory-side RMWs (~32B HBM write
// each) -- 3.2M atomics in count_kernel cost 100MB WRITE / 137us. R7: CSR is
// built with ZERO global atomics: per-block LDS histograms + plain scans +
// per-block reserved ranges; all tickets are LDS atomics only.

#define IN_CH 128
#define HID 128
#define OUT_CH 64
#define NBLK 128          // chunk blocks for hist/scatter
#define MAXNB 1568        // >= ceil(100000/64)=1563 buckets

typedef unsigned int uint_t;
typedef unsigned short ushort_t;

__device__ __forceinline__ ushort_t f32_to_bf16_rn(float f) {
    uint_t u = __float_as_uint(f);
    u = (u + 0x7fffu + ((u >> 16) & 1u)) >> 16;
    return (ushort_t)u;
}
__device__ __forceinline__ float bf16lo_to_f32(uint_t u) { return __uint_as_float(u << 16); }
__device__ __forceinline__ float bf16hi_to_f32(uint_t u) { return __uint_as_float(u & 0xffff0000u); }

// ---------------- phase 1: per-block LDS bucket histogram ----------------
__global__ __launch_bounds__(256) void hist_kernel(const int* __restrict__ dst, int E,
                                                   int chunk, int NB,
                                                   int* __restrict__ blk_cnt) {
    __shared__ int hist[MAXNB];
    int tid = threadIdx.x;
    int blk = blockIdx.x;
    for (int b = tid; b < NB; b += 256) hist[b] = 0;
    __syncthreads();
    int start = blk * chunk;
    int end = start + chunk; if (end > E) end = E;
    int e = start + tid;
    for (; e + 768 < end; e += 1024) {
        int d0 = dst[e], d1 = dst[e + 256], d2 = dst[e + 512], d3 = dst[e + 768];
        atomicAdd(&hist[d0 >> 6], 1);
        atomicAdd(&hist[d1 >> 6], 1);
        atomicAdd(&hist[d2 >> 6], 1);
        atomicAdd(&hist[d3 >> 6], 1);
    }
    for (; e < end; e += 256) atomicAdd(&hist[dst[e] >> 6], 1);
    __syncthreads();
    for (int b = tid; b < NB; b += 256) blk_cnt[blk * NB + b] = hist[b];
}

// ---------------- phase 2a: bucket totals (column sums) ----------------
__global__ __launch_bounds__(256) void btot_kernel(const int* __restrict__ blk_cnt,
                                                   int NB, int* __restrict__ btot) {
    int b = blockIdx.x * 256 + threadIdx.x;
    if (b < NB) {
        int sum = 0;
        #pragma unroll 8
        for (int blk = 0; blk < NBLK; blk++) sum += blk_cnt[blk * NB + b];
        btot[b] = sum;
    }
}

// ---------------- phase 2b: single-block exclusive scan over buckets --------------
__global__ __launch_bounds__(256) void scan_kernel(const int* __restrict__ btot, int NB,
                                                   int* __restrict__ bucket_base,
                                                   int* __restrict__ row_start,
                                                   int n, int E) {
    __shared__ int sdata[256];
    __shared__ int carryS;
    int tid = threadIdx.x;
    if (tid == 0) carryS = 0;
    __syncthreads();
    int nchunks = (NB + 255) / 256;
    for (int c = 0; c < nchunks; c++) {
        int i = c * 256 + tid;
        int v = (i < NB) ? btot[i] : 0;
        sdata[tid] = v;
        __syncthreads();
        for (int off = 1; off < 256; off <<= 1) {
            int t = (tid >= off) ? sdata[tid - off] : 0;
            __syncthreads();
            sdata[tid] += t;
            __syncthreads();
        }
        if (i < NB) bucket_base[i] = carryS + sdata[tid] - v;
        __syncthreads();
        if (tid == 0) carryS += sdata[255];
        __syncthreads();
    }
    if (tid == 0) {
        bucket_base[NB] = E;
        row_start[n] = E;
    }
}

// ---------------- phase 2c: per-bucket exclusive scan over blocks -----------------
// 16 buckets per workgroup; tile [NBLK][16]; writes blk_start[blk*NB + b].
__global__ __launch_bounds__(256) void colscan_kernel(const int* __restrict__ blk_cnt,
                                                      const int* __restrict__ bucket_base,
                                                      int NB, int* __restrict__ blk_start) {
    __shared__ int tile[NBLK][16];
    int tid = threadIdx.x;
    int b0 = blockIdx.x * 16;
    for (int idx = tid; idx < NBLK * 16; idx += 256) {
        int blk = idx >> 4, b = idx & 15;
        if (b0 + b < NB) tile[blk][b] = blk_cnt[blk * NB + b0 + b];
    }
    __syncthreads();
    if (tid < 16 && b0 + tid < NB) {
        int running = bucket_base[b0 + tid];
        for (int blk = 0; blk < NBLK; blk++) {
            int t = tile[blk][tid];
            tile[blk][tid] = running;
            running += t;
        }
    }
    __syncthreads();
    for (int idx = tid; idx < NBLK * 16; idx += 256) {
        int blk = idx >> 4, b = idx & 15;
        if (b0 + b < NB) blk_start[blk * NB + b0 + b] = tile[blk][b];
    }
}

// ---------------- phase 3: scatter, LDS tickets only ----------------
// pack: src (26 bits) | (dst & 63) << 26.
__global__ __launch_bounds__(256) void scatter_kernel(const int* __restrict__ src,
                                                      const int* __restrict__ dst,
                                                      int E, int chunk, int NB,
                                                      const int* __restrict__ blk_start,
                                                      uint_t* __restrict__ pairs) {
    __shared__ int cur[MAXNB];
    int tid = threadIdx.x;
    int blk = blockIdx.x;
    for (int b = tid; b < NB; b += 256) cur[b] = blk_start[blk * NB + b];
    __syncthreads();
    int start = blk * chunk;
    int end = start + chunk; if (end > E) end = E;
    int e = start + tid;
    for (; e + 768 < end; e += 1024) {
        int d0 = dst[e], d1 = dst[e + 256], d2 = dst[e + 512], d3 = dst[e + 768];
        int s0 = src[e], s1 = src[e + 256], s2 = src[e + 512], s3 = src[e + 768];
        int p0 = atomicAdd(&cur[d0 >> 6], 1);
        int p1 = atomicAdd(&cur[d1 >> 6], 1);
        int p2 = atomicAdd(&cur[d2 >> 6], 1);
        int p3 = atomicAdd(&cur[d3 >> 6], 1);
        pairs[p0] = (uint_t)s0 | ((uint_t)(d0 & 63) << 26);
        pairs[p1] = (uint_t)s1 | ((uint_t)(d1 & 63) << 26);
        pairs[p2] = (uint_t)s2 | ((uint_t)(d2 & 63) << 26);
        pairs[p3] = (uint_t)s3 | ((uint_t)(d3 & 63) << 26);
    }
    for (; e < end; e += 256) {
        int d = dst[e], s = src[e];
        int p = atomicAdd(&cur[d >> 6], 1);
        pairs[p] = (uint_t)s | ((uint_t)(d & 63) << 26);
    }
}

// ---------------- phase 4: fine fill -- per bucket: counts, row_start, dinv, csr ---
__global__ __launch_bounds__(256) void fine_fill_kernel(const uint_t* __restrict__ pairs,
                                                        const int* __restrict__ bucket_base,
                                                        int* __restrict__ row_start,
                                                        float* __restrict__ dinv,
                                                        int* __restrict__ csr_src,
                                                        int n) {
    __shared__ int cnt64[64];
    __shared__ int cur[64];
    int b = blockIdx.x;
    int node0 = b << 6;
    int tid = threadIdx.x;
    if (tid < 64) cnt64[tid] = 0;
    __syncthreads();
    int start = bucket_base[b];
    int end = bucket_base[b + 1];
    // pass A: node-local histogram
    int e = start + tid;
    for (; e + 768 < end; e += 1024) {
        uint_t u0 = pairs[e], u1 = pairs[e + 256], u2 = pairs[e + 512], u3 = pairs[e + 768];
        atomicAdd(&cnt64[u0 >> 26], 1);
        atomicAdd(&cnt64[u1 >> 26], 1);
        atomicAdd(&cnt64[u2 >> 26], 1);
        atomicAdd(&cnt64[u3 >> 26], 1);
    }
    for (; e < end; e += 256) atomicAdd(&cnt64[pairs[e] >> 26], 1);
    __syncthreads();
    // wave 0: exclusive prefix over 64 node counts; emit row_start/dinv/cursors
    if (tid < 64) {
        int c = cnt64[tid];
        int v = c;
        #pragma unroll
        for (int off = 1; off < 64; off <<= 1) {
            int u = __shfl_up(v, off, 64);
            if (tid >= off) v += u;
        }
        int excl = start + v - c;
        if (node0 + tid < n) {
            row_start[node0 + tid] = excl;
            dinv[node0 + tid] = rsqrtf((float)(c + 1));  // +1 self loop
        }
        cur[tid] = excl;
    }
    __syncthreads();
    // pass B: place src indices node-sorted
    e = start + tid;
    for (; e + 768 < end; e += 1024) {
        uint_t u0 = pairs[e], u1 = pairs[e + 256], u2 = pairs[e + 512], u3 = pairs[e + 768];
        int p0 = atomicAdd(&cur[u0 >> 26], 1);
        int p1 = atomicAdd(&cur[u1 >> 26], 1);
        int p2 = atomicAdd(&cur[u2 >> 26], 1);
        int p3 = atomicAdd(&cur[u3 >> 26], 1);
        csr_src[p0] = (int)(u0 & 0x3FFFFFFu);
        csr_src[p1] = (int)(u1 & 0x3FFFFFFu);
        csr_src[p2] = (int)(u2 & 0x3FFFFFFu);
        csr_src[p3] = (int)(u3 & 0x3FFFFFFu);
    }
    for (; e < end; e += 256) {
        uint_t u = pairs[e];
        int p = atomicAdd(&cur[u >> 26], 1);
        csr_src[p] = (int)(u & 0x3FFFFFFu);
    }
}

// ---------------- GEMM: Y[n x NCOL] = X[n x 128] * W[128 x NCOL] ----------------
template <int NCOL, bool BF16_IN>
__global__ __launch_bounds__(256, 3) void gemm_kernel(const void* __restrict__ Xv,
                                                      const float* __restrict__ W,
                                                      ushort_t* __restrict__ Y, int nrows) {
    constexpr int K = 128;
    constexpr int KT = 32;
    constexpr int CPL = NCOL / 64;       // cols per lane (2 or 1)
    __shared__ __align__(16) float Xs[64 * K];      // 32 KB
    __shared__ __align__(16) float Ws[KT * NCOL];   // 16 KB / 8 KB

    int tid = threadIdx.x;
    int wave = tid >> 6;
    int lane = tid & 63;
    int rowBase = blockIdx.x * 64;
    int r0 = wave * 16;

    if (BF16_IN) {
        const uint_t* X = (const uint_t*)Xv;
        for (int j = tid; j < 64 * (K / 2); j += 256) {
            int r = j >> 6;
            int c = j & 63;
            int gr = rowBase + r;
            uint_t u = (gr < nrows) ? X[(size_t)gr * (K / 2) + c] : 0u;
            Xs[r * K + 2 * c]     = bf16lo_to_f32(u);
            Xs[r * K + 2 * c + 1] = bf16hi_to_f32(u);
        }
    } else {
        const float4* X4 = (const float4*)Xv;
        float4* Xs4 = (float4*)Xs;
        for (int j = tid; j < 64 * (K / 4); j += 256) {
            int r = j >> 5;
            int gr = rowBase + r;
            float4 v = make_float4(0.f, 0.f, 0.f, 0.f);
            if (gr < nrows) v = X4[(size_t)gr * (K / 4) + (j & 31)];
            Xs4[j] = v;
        }
    }

    float acc[16][CPL];
    #pragma unroll
    for (int r = 0; r < 16; r++)
        #pragma unroll
        for (int c = 0; c < CPL; c++) acc[r][c] = 0.f;

    #pragma unroll 1
    for (int kt = 0; kt < K; kt += KT) {
        __syncthreads();
        {
            float4* Ws4 = (float4*)Ws;
            const float4* W4 = (const float4*)W;
            for (int j = tid; j < KT * (NCOL / 4); j += 256)
                Ws4[j] = W4[(size_t)kt * (NCOL / 4) + j];
        }
        __syncthreads();
        #pragma unroll 2
        for (int k4 = 0; k4 < KT; k4 += 4) {
            float wv[4][CPL];
            #pragma unroll
            for (int kk = 0; kk < 4; kk++)
                #pragma unroll
                for (int c = 0; c < CPL; c++)
                    wv[kk][c] = Ws[(k4 + kk) * NCOL + lane * CPL + c];
            #pragma unroll
            for (int r = 0; r < 16; r++) {
                float4 xv = *(const float4*)&Xs[(r0 + r) * K + kt + k4];  // broadcast
                #pragma unroll
                for (int c = 0; c < CPL; c++) {
                    acc[r][c] = fmaf(xv.x, wv[0][c], acc[r][c]);
                    acc[r][c] = fmaf(xv.y, wv[1][c], acc[r][c]);
                    acc[r][c] = fmaf(xv.z, wv[2][c], acc[r][c]);
                    acc[r][c] = fmaf(xv.w, wv[3][c], acc[r][c]);
                }
            }
        }
    }

    #pragma unroll
    for (int r = 0; r < 16; r++) {
        int gr = rowBase + r0 + r;
        if (gr < nrows) {
            if (CPL == 2) {
                uint_t u = (uint_t)f32_to_bf16_rn(acc[r][0]) |
                           ((uint_t)f32_to_bf16_rn(acc[r][CPL - 1]) << 16);
                ((uint_t*)(Y + (size_t)gr * NCOL))[lane] = u;
            } else {
                Y[(size_t)gr * NCOL + lane] = f32_to_bf16_rn(acc[r][0]);
            }
        }
    }
}

// ---------------- aggregation layer 1: pull + bias + relu + L2 rownorm ----------------
__global__ __launch_bounds__(256) void agg1_kernel(const ushort_t* __restrict__ xw,
                                                   const int* __restrict__ csr_src,
                                                   const int* __restrict__ row_start,
                                                   const float* __restrict__ dinv,
                                                   const float* __restrict__ b1,
                                                   ushort_t* __restrict__ h, int n) {
    int wid = (blockIdx.x * 256 + threadIdx.x) >> 6;
    int lane = threadIdx.x & 63;
    if (wid >= n) return;
    int i = wid;
    float di = dinv[i];
    float sc = di * di;
    uint_t su = ((const uint_t*)(xw + (size_t)i * HID))[lane];
    float ax = bf16lo_to_f32(su) * sc, ay = bf16hi_to_f32(su) * sc;
    int e0 = row_start[i], e1 = row_start[i + 1];
    int e = e0;
    for (; e + 8 <= e1; e += 8) {
        int s[8];
        #pragma unroll
        for (int j = 0; j < 8; j++) s[j] = csr_src[e + j];
        float dv[8];
        #pragma unroll
        for (int j = 0; j < 8; j++) dv[j] = dinv[s[j]];
        uint_t v[8];
        #pragma unroll
        for (int j = 0; j < 8; j++)
            v[j] = ((const uint_t*)(xw + (size_t)s[j] * HID))[lane];
        #pragma unroll
        for (int j = 0; j < 8; j++) {
            float c = dv[j] * di;
            ax = fmaf(bf16lo_to_f32(v[j]), c, ax);
            ay = fmaf(bf16hi_to_f32(v[j]), c, ay);
        }
    }
    for (; e < e1; e++) {
        int s = csr_src[e];
        float c = dinv[s] * di;
        uint_t v = ((const uint_t*)(xw + (size_t)s * HID))[lane];
        ax = fmaf(bf16lo_to_f32(v), c, ax);
        ay = fmaf(bf16hi_to_f32(v), c, ay);
    }
    ax += b1[lane * 2];
    ay += b1[lane * 2 + 1];
    ax = fmaxf(ax, 0.f);
    ay = fmaxf(ay, 0.f);
    float ss = ax * ax + ay * ay;
    #pragma unroll
    for (int m = 32; m >= 1; m >>= 1) ss += __shfl_xor(ss, m, 64);
    float scale = 1.0f / fmaxf(sqrtf(ss), 1e-12f);
    uint_t u = (uint_t)f32_to_bf16_rn(ax * scale) |
               ((uint_t)f32_to_bf16_rn(ay * scale) << 16);
    ((uint_t*)(h + (size_t)i * HID))[lane] = u;
}

// ---------------- aggregation layer 2: pull + bias -> d_out (f32) ----------------
__global__ __launch_bounds__(256) void agg2_kernel(const ushort_t* __restrict__ hw,
                                                   const int* __restrict__ csr_src,
                                                   const int* __restrict__ row_start,
                                                   const float* __restrict__ dinv,
                                                   const float* __restrict__ b2,
                                                   float* __restrict__ out, int n) {
    int wid = (blockIdx.x * 256 + threadIdx.x) >> 6;
    int lane = threadIdx.x & 63;
    int i = wid * 2 + (lane >> 5);
    int l = lane & 31;
    if (i >= n) return;
    float di = dinv[i];
    float sc = di * di;
    uint_t su = ((const uint_t*)(hw + (size_t)i * OUT_CH))[l];
    float ax = bf16lo_to_f32(su) * sc, ay = bf16hi_to_f32(su) * sc;
    int e0 = row_start[i], e1 = row_start[i + 1];
    int e = e0;
    for (; e + 8 <= e1; e += 8) {
        int s[8];
        #pragma unroll
        for (int j = 0; j < 8; j++) s[j] = csr_src[e + j];
        float dv[8];
        #pragma unroll
        for (int j = 0; j < 8; j++) dv[j] = dinv[s[j]];
        uint_t v[8];
        #pragma unroll
        for (int j = 0; j < 8; j++)
            v[j] = ((const uint_t*)(hw + (size_t)s[j] * OUT_CH))[l];
        #pragma unroll
        for (int j = 0; j < 8; j++) {
            float c = dv[j] * di;
            ax = fmaf(bf16lo_to_f32(v[j]), c, ax);
            ay = fmaf(bf16hi_to_f32(v[j]), c, ay);
        }
    }
    for (; e < e1; e++) {
        int s = csr_src[e];
        float c = dinv[s] * di;
        uint_t v = ((const uint_t*)(hw + (size_t)s * OUT_CH))[l];
        ax = fmaf(bf16lo_to_f32(v), c, ax);
        ay = fmaf(bf16hi_to_f32(v), c, ay);
    }
    ax += b2[l * 2];
    ay += b2[l * 2 + 1];
    ((float2*)(out + (size_t)i * OUT_CH))[l] = make_float2(ax, ay);
}

extern "C" void kernel_launch(void* const* d_in, const int* in_sizes, int n_in,
                              void* d_out, int out_size, void* d_ws, size_t ws_size,
                              hipStream_t stream) {
    const float* x  = (const float*)d_in[0];
    const int*   ei = (const int*)d_in[1];
    const float* W1 = (const float*)d_in[2];
    const float* b1 = (const float*)d_in[3];
    const float* W2 = (const float*)d_in[4];
    const float* b2 = (const float*)d_in[5];
    float* out = (float*)d_out;

    const int N = in_sizes[0] / IN_CH;     // 100000
    const int E = in_sizes[1] / 2;         // 1600000
    const int* src = ei;
    const int* dst = ei + E;
    const int NB = (N + 63) / 64;          // buckets (1563)
    const int chunk = (E + NBLK - 1) / NBLK;

    // ---- workspace carve ----
    char* base = (char*)d_ws;
    size_t off = 0;
    auto alloc = [&](size_t bytes) -> void* {
        void* p = base + off;
        off = (off + bytes + 255) & ~(size_t)255;
        return p;
    };
    int*      blk_cnt     = (int*)alloc((size_t)NBLK * NB * 4);
    int*      blk_start   = (int*)alloc((size_t)NBLK * NB * 4);
    int*      btot        = (int*)alloc((size_t)NB * 4);
    int*      bucket_base = (int*)alloc((size_t)(NB + 1) * 4);
    int*      row_start   = (int*)alloc((size_t)(N + 1) * 4);
    float*    dinv        = (float*)alloc((size_t)N * 4);
    int*      csr_src     = (int*)alloc((size_t)E * 4);
    uint_t*   pairs       = (uint_t*)alloc((size_t)E * 4);
    ushort_t* xw          = (ushort_t*)alloc((size_t)N * HID * 2);
    ushort_t* h           = (ushort_t*)alloc((size_t)N * HID * 2);
    ushort_t* hw          = (ushort_t*)alloc((size_t)N * OUT_CH * 2);
    (void)ws_size;

    // CSR build -- no global atomics anywhere
    hist_kernel<<<NBLK, 256, 0, stream>>>(dst, E, chunk, NB, blk_cnt);
    btot_kernel<<<(NB + 255) / 256, 256, 0, stream>>>(blk_cnt, NB, btot);
    scan_kernel<<<1, 256, 0, stream>>>(btot, NB, bucket_base, row_start, N, E);
    colscan_kernel<<<(NB + 15) / 16, 256, 0, stream>>>(blk_cnt, bucket_base, NB, blk_start);
    scatter_kernel<<<NBLK, 256, 0, stream>>>(src, dst, E, chunk, NB, blk_start, pairs);
    fine_fill_kernel<<<NB, 256, 0, stream>>>(pairs, bucket_base, row_start, dinv,
                                             csr_src, N);

    // layer 1
    gemm_kernel<128, false><<<(N + 63) / 64, 256, 0, stream>>>(x, W1, xw, N);
    agg1_kernel<<<(N * 64 + 255) / 256, 256, 0, stream>>>(xw, csr_src, row_start,
                                                          dinv, b1, h, N);
    // layer 2
    gemm_kernel<64, true><<<(N + 63) / 64, 256, 0, stream>>>(h, W2, hw, N);
    int waves2 = (N + 1) / 2;
    agg2_kernel<<<(waves2 * 64 + 255) / 256, 256, 0, stream>>>(hw, csr_src, row_start,
                                                               dinv, b2, out, N);
}